// Round 10
// baseline (623.198 us; speedup 1.0000x reference)
//
#include <hip/hip_runtime.h>

#define NN 20000
#define NNP 20096       // padded rows: 314*64
#define NEIGH 12
#define NCRYS 20
#define NSUB 16         // pooled partial-sum split

typedef __bf16 bf16x8 __attribute__((ext_vector_type(8)));
typedef __bf16 bf16x4 __attribute__((ext_vector_type(4)));
typedef float f32x4 __attribute__((ext_vector_type(4)));

// ============================================================
// pack: W[k][n] -> bf16 MFMA-B frag layout Wp[kt][nt][k8][ni][j]
// ============================================================
__device__ __forceinline__ void pack_one(const float* Wrel, const float* Wroot,
                                         __bf16* Wp, int K, int idx) {
    int k = idx >> 8, n = idx & 255;
    int r = n >> 6, h = n & 63;
    float v = (r < 3) ? Wrel[((size_t)r * K + k) * 64 + h] : Wroot[(size_t)k * 64 + h];
    int kt = k >> 5, k8 = (k >> 3) & 3, j = k & 7, nt = n >> 4, ni = n & 15;
    Wp[((((size_t)kt * 16 + nt) * 4 + k8) * 16 + ni) * 8 + j] = (__bf16)v;
}

// ============================================================
// setup: build_adj (938) + pack (256, strided) + transpose (628)
// ============================================================
__global__ __launch_bounds__(256) void setup_kernel(
    const int* __restrict__ species, const int* __restrict__ nbr,
    int* __restrict__ adj, int* __restrict__ deg,
    const float* __restrict__ W1b_rel, const float* __restrict__ W1b_root,
    const float* __restrict__ W1a_rel, const float* __restrict__ W1a_root,
    const float* __restrict__ W2b_rel, const float* __restrict__ W2b_root,
    const float* __restrict__ W2a_rel, const float* __restrict__ W2a_root,
    __bf16* __restrict__ Wp1b, __bf16* __restrict__ Wp1a,
    __bf16* __restrict__ Wp2b, __bf16* __restrict__ Wp2a,
    const float* __restrict__ bond, const float* __restrict__ angle,
    float* __restrict__ bondT, float* __restrict__ angleT) {
    __shared__ float ls[64 * 145];
    const int bx = blockIdx.x, tid = threadIdx.x;
    if (bx < 938) {
        int e = bx * 256 + tid;
        if (e < NN * NEIGH) {
            int i = e / NEIGH;
            int d = nbr[e];
            int r = species[i] + species[d];
            int slot = atomicAdd(&deg[d], 1);
            if (slot < 64) adj[(size_t)d * 64 + slot] = i | (r << 28);
        }
    } else if (bx < 938 + 256) {
        const int S0 = 480 * 256, S1 = S0 + 2880 * 256, S2 = S1 + 64 * 256, S3 = S2 + 64 * 256;
        for (int idx = (bx - 938) * 256 + tid; idx < S3; idx += 256 * 256) {
            if (idx < S0)       pack_one(W1b_rel, W1b_root, Wp1b, 480, idx);
            else if (idx < S1)  pack_one(W1a_rel, W1a_root, Wp1a, 2880, idx - S0);
            else if (idx < S2)  pack_one(W2b_rel, W2b_root, Wp2b, 64, idx - S1);
            else                pack_one(W2a_rel, W2a_root, Wp2a, 64, idx - S2);
        }
    } else {
        int tb = bx - 1194;
        if (tb < 314) {
            int m0 = tb * 64;
            for (int idx = tid; idx < 64 * 144; idx += 256) {
                int mm = idx / 144, j = idx - mm * 144;
                int m = m0 + mm;
                ls[mm * 145 + j] = (m < NN) ? angle[(size_t)m * 144 + j] : 0.f;
            }
            __syncthreads();
            for (int idx = tid; idx < 144 * 64; idx += 256) {
                int j = idx >> 6, mm = idx & 63;
                angleT[(size_t)j * NNP + m0 + mm] = ls[mm * 145 + j];
            }
        } else {
            int m0 = (tb - 314) * 64;
            for (int idx = tid; idx < 64 * 12; idx += 256) {
                int mm = idx / 12, j = idx - mm * 12;
                int m = m0 + mm;
                ls[mm * 13 + j] = (m < NN) ? bond[(size_t)m * 12 + j] : 0.f;
            }
            __syncthreads();
            for (int idx = tid; idx < 12 * 64; idx += 256) {
                int j = idx >> 6, mm = idx & 63;
                bondT[(size_t)j * NNP + m0 + mm] = ls[mm * 13 + j];
            }
        }
    }
}

// ============================================================
// gemm1 (R7/R9 structure, proven 53 us): 64x256 tile, 512 threads.
// ============================================================
template <int MODE>  // 0: bond K=480 DIVN=40; 1: angle K=2880 DIVN=20
__device__ __forceinline__ void gemm1_body(const float* __restrict__ xT,
                                           const __bf16* __restrict__ Wp,
                                           float* __restrict__ Y, int mb,
                                           __bf16* __restrict__ Al) {
    constexpr int KTOT = (MODE == 0) ? 480 : 2880;
    constexpr int NKT = KTOT / 32;
    constexpr int DIVN = (MODE == 0) ? 40 : 20;
    constexpr float F0 = (MODE == 0) ? 0.f : -1.f;
    constexpr float FS = (MODE == 0) ? (8.f / 39.f) : (2.f / 19.f);
    constexpr float NG2 = ((MODE == 0) ? -25.f : -100.f) * 1.44269504f;
    const float C  = __builtin_amdgcn_exp2f(2.f * NG2 * FS * FS);
    const float P1 = NG2 * FS * FS;
    const float P2 = -2.f * NG2 * FS;

    const int tid = threadIdx.x;
    const int lane = tid & 63, wv = tid >> 6;
    const int m0 = mb * 64;
    const int smt = tid >> 7;
    const int sk8 = (tid >> 5) & 3;
    const int smi = (tid >> 1) & 15;
    const int sjh = (tid & 1) * 4;
    const int sgm = m0 + smt * 16 + smi;
    const int kk0 = sk8 * 8 + sjh;
    const int swoff = (((smt * 4 + sk8) * 16 + smi) * 8 + sjh);
    const int k8b = lane >> 4, nib = lane & 15;
    const bf16x8* Bg = (const bf16x8*)Wp;

    f32x4 acc[4][2] = {};
    bf16x8 bcur[2], bnx[2], bnx2[2];

    auto bload = [&](int kt, bf16x8* d) {
#pragma unroll
        for (int jf = 0; jf < 2; ++jf)
            d[jf] = Bg[(((size_t)kt * 16 + 2 * wv + jf) * 4 + k8b) * 16 + nib];
    };
    auto aload = [&](int kt) -> float {
        int k = kt * 32 + kk0;
        int jr = k / DIVN;
        return xT[(size_t)jr * NNP + sgm];
    };
    auto stage = [&](int kt, float a, __bf16* dst) {
        int k = kt * 32 + kk0;
        int jr = k / DIVN;
        int s = k - jr * DIVN;
        float d0 = a - (F0 + (float)s * FS);
        float e0 = __builtin_amdgcn_exp2f(NG2 * d0 * d0);
        float q0 = __builtin_amdgcn_exp2f(fmaf(P2, d0, P1));
        float e1 = e0 * q0;
        float q1 = q0 * C;
        float e2 = e1 * q1;
        float e3 = e2 * q1 * C;
        bf16x4 vals;
        vals[0] = (__bf16)e0; vals[1] = (__bf16)e1;
        vals[2] = (__bf16)e2; vals[3] = (__bf16)e3;
        *(bf16x4*)&dst[swoff] = vals;
    };

    {
        float a0 = aload(0);
        stage(0, a0, Al);
    }
    float anext = aload(1 < NKT ? 1 : 0);
    bload(0, bcur);
    bload(1 < NKT ? 1 : 0, bnx);
    __syncthreads();

    for (int kt = 0; kt < NKT; ++kt) {
        __bf16* Ab = Al + ((kt & 1) << 11);
        __bf16* An = Al + (((kt & 1) ^ 1) << 11);
        const int ktp2 = (kt + 2 < NKT) ? kt + 2 : NKT - 1;
        bload(ktp2, bnx2);
        float afut = (kt + 2 < NKT) ? aload(kt + 2) : anext;
        bf16x8 af[4];
#pragma unroll
        for (int t = 0; t < 4; ++t)
            af[t] = *(const bf16x8*)&Ab[((((t << 2) + k8b) << 4) + nib) << 3];
#pragma unroll
        for (int i = 0; i < 4; ++i)
#pragma unroll
            for (int j = 0; j < 2; ++j)
                acc[i][j] = __builtin_amdgcn_mfma_f32_16x16x32_bf16(af[i], bcur[j], acc[i][j], 0, 0, 0);
        if (kt + 1 < NKT)
            stage(kt + 1, anext, An);
        __syncthreads();
#pragma unroll
        for (int j = 0; j < 2; ++j) { bcur[j] = bnx[j]; bnx[j] = bnx2[j]; }
        anext = afut;
    }

    const int mrow0 = m0 + ((lane >> 4) << 2);
    const int ncol = (wv << 5) + nib;
#pragma unroll
    for (int i = 0; i < 4; ++i)
#pragma unroll
        for (int j = 0; j < 2; ++j)
#pragma unroll
            for (int v = 0; v < 4; ++v) {
                int m = mrow0 + i * 16 + v;
                if (m < NN) Y[(size_t)m * 256 + ncol + j * 16] = acc[i][j][v];
            }
}

__global__ __launch_bounds__(512, 4) void mega_gemm1(const float* __restrict__ bondT,
                                                     const float* __restrict__ angleT,
                                                     const __bf16* __restrict__ Wp1b,
                                                     const __bf16* __restrict__ Wp1a,
                                                     float* __restrict__ Yb, float* __restrict__ Ya) {
    __shared__ __align__(16) __bf16 Al[2 * 2048];
    int bx = blockIdx.x;
    if (bx < 314) gemm1_body<1>(angleT, Wp1a, Ya, bx, Al);
    else          gemm1_body<0>(bondT, Wp1b, Yb, bx - 314, Al);
}

// ============================================================
// agg pair core (R9): two nodes per wave, batched gathers
// ============================================================
__device__ __forceinline__ void agg_pair(const float* __restrict__ Y,
                                         const int* __restrict__ adj,
                                         const int* __restrict__ deg,
                                         const float* __restrict__ bias,
                                         int nodeA, int nodeB, int h,
                                         float& oA, float& oB) {
    bool hasA = nodeA < NN, hasB = nodeB < NN;
    int dgA = hasA ? min(deg[nodeA], 64) : 0;
    int dgB = hasB ? min(deg[nodeB], 64) : 0;
    int eA = hasA ? adj[(size_t)nodeA * 64 + h] : 0;
    int eB = hasB ? adj[(size_t)nodeB * 64 + h] : 0;
    float rootA = hasA ? Y[(size_t)nodeA * 256 + 192 + h] : 0.f;
    float rootB = hasB ? Y[(size_t)nodeB * 256 + 192 + h] : 0.f;
    bool vA = h < dgA, vB = h < dgB;
    int rA = eA >> 28, rB = eB >> 28;
    int cA0 = __popcll(__ballot(vA && rA == 0));
    int cA1 = __popcll(__ballot(vA && rA == 1));
    int cA2 = __popcll(__ballot(vA && rA == 2));
    int cB0 = __popcll(__ballot(vB && rB == 0));
    int cB1 = __popcll(__ballot(vB && rB == 1));
    int cB2 = __popcll(__ballot(vB && rB == 2));
    int ecA = vA ? eA : 0;
    int ecB = vB ? eB : 0;
    float sA0 = 0.f, sA1 = 0.f, sA2 = 0.f, sB0 = 0.f, sB1 = 0.f, sB2 = 0.f;
    int maxdg = max(dgA, dgB);
    for (int k0 = 0; k0 < maxdg; k0 += 16) {
        float va[16], vb[16];
        int ea[16], eb[16];
        bool doA = k0 < dgA, doB = k0 < dgB;
        if (doA) {
#pragma unroll
            for (int i = 0; i < 16; ++i) {
                ea[i] = __builtin_amdgcn_readlane(ecA, k0 + i);
                va[i] = Y[(size_t)(ea[i] & 0x0FFFFFFF) * 256 + (ea[i] >> 28) * 64 + h];
            }
        }
        if (doB) {
#pragma unroll
            for (int i = 0; i < 16; ++i) {
                eb[i] = __builtin_amdgcn_readlane(ecB, k0 + i);
                vb[i] = Y[(size_t)(eb[i] & 0x0FFFFFFF) * 256 + (eb[i] >> 28) * 64 + h];
            }
        }
        if (doA) {
#pragma unroll
            for (int i = 0; i < 16; ++i) {
                if (k0 + i < dgA) {
                    int rr = ea[i] >> 28;
                    if (rr == 0) sA0 += va[i];
                    else if (rr == 1) sA1 += va[i];
                    else sA2 += va[i];
                }
            }
        }
        if (doB) {
#pragma unroll
            for (int i = 0; i < 16; ++i) {
                if (k0 + i < dgB) {
                    int rr = eb[i] >> 28;
                    if (rr == 0) sB0 += vb[i];
                    else if (rr == 1) sB1 += vb[i];
                    else sB2 += vb[i];
                }
            }
        }
    }
    float bh = bias[h];
    oA = hasA ? fmaxf(rootA + bh + sA0 / fmaxf((float)cA0, 1.f) +
                      sA1 / fmaxf((float)cA1, 1.f) + sA2 / fmaxf((float)cA2, 1.f), 0.f)
              : 0.f;
    oB = hasB ? fmaxf(rootB + bh + sB0 / fmaxf((float)cB0, 1.f) +
                      sB1 / fmaxf((float)cB1, 1.f) + sB2 / fmaxf((float)cB2, 1.f), 0.f)
              : 0.f;
}

// ============================================================
// agg1 + gemm2 fused: block = 16 nodes = one MFMA m-tile.
// Gather -> H in LDS (A-frag layout) -> 8 MFMA vs register W2 frags
// (prefetched before the gather walls) -> write layer-2 Y directly.
// ============================================================
__global__ __launch_bounds__(256) void agg_gemm2(const float* __restrict__ Yb,
                                                 const float* __restrict__ Ya,
                                                 const int* __restrict__ adj,
                                                 const int* __restrict__ deg,
                                                 const float* __restrict__ biasb,
                                                 const float* __restrict__ biasa,
                                                 const __bf16* __restrict__ Wp2b,
                                                 const __bf16* __restrict__ Wp2a,
                                                 float* __restrict__ Y2b,
                                                 float* __restrict__ Y2a) {
    const float* Y = blockIdx.y ? Ya : Yb;
    const float* bias = blockIdx.y ? biasa : biasb;
    const __bf16* Wp = blockIdx.y ? Wp2a : Wp2b;
    float* Y2 = blockIdx.y ? Y2a : Y2b;
    __shared__ __align__(16) __bf16 Hl[1024];  // [kt 2][k8 4][mi 16][j 8]
    const int wv = threadIdx.x >> 6, lane = threadIdx.x & 63;
    const int h = lane;
    const int base = blockIdx.x * 16;
    // ---- B prefetch (independent of gathers; in flight across them) ----
    const int k8b = lane >> 4, nib = lane & 15;
    const bf16x8* Bg = (const bf16x8*)Wp;
    bf16x8 bfr[2][4];
#pragma unroll
    for (int kt = 0; kt < 2; ++kt)
#pragma unroll
        for (int t = 0; t < 4; ++t)
            bfr[kt][t] = Bg[(((size_t)kt * 16 + wv * 4 + t) * 4 + k8b) * 16 + nib];
    // ---- gather 4 nodes per wave (2 pairs) ----
    const int hkt = h >> 5, hk8 = (h >> 3) & 3, hj = h & 7;
#pragma unroll
    for (int p = 0; p < 2; ++p) {
        int nodeA = base + wv * 4 + p * 2;
        int nodeB = nodeA + 1;
        float oA, oB;
        agg_pair(Y, adj, deg, bias, nodeA, nodeB, h, oA, oB);
        int mi = wv * 4 + p * 2;
        Hl[((hkt * 4 + hk8) * 16 + mi) * 8 + hj] = (__bf16)oA;
        Hl[((hkt * 4 + hk8) * 16 + mi + 1) * 8 + hj] = (__bf16)oB;
    }
    __syncthreads();
    // ---- MFMA: 16 rows x 64 cols per wave ----
    bf16x8 af[2];
#pragma unroll
    for (int kt = 0; kt < 2; ++kt)
        af[kt] = *(const bf16x8*)&Hl[((kt * 4 + k8b) * 16 + nib) * 8];
    f32x4 acc[4] = {};
#pragma unroll
    for (int kt = 0; kt < 2; ++kt)
#pragma unroll
        for (int t = 0; t < 4; ++t)
            acc[t] = __builtin_amdgcn_mfma_f32_16x16x32_bf16(af[kt], bfr[kt][t], acc[t], 0, 0, 0);
    // ---- epilogue: row=(lane>>4)*4+v (node), col=wv*64+t*16+(lane&15) ----
    const int r0 = (lane >> 4) << 2;
    const int c0 = wv * 64 + nib;
#pragma unroll
    for (int t = 0; t < 4; ++t)
#pragma unroll
        for (int v = 0; v < 4; ++v) {
            int node = base + r0 + v;
            if (node < NN) Y2[(size_t)node * 256 + c0 + t * 16] = acc[t][v];
        }
}

// ============================================================
// agg2 + pooling + final FC (last-block pattern)
// ============================================================
__global__ __launch_bounds__(256) void agg_pool_final(const float* __restrict__ Yb,
                                                      const float* __restrict__ Ya,
                                                      const int* __restrict__ adj,
                                                      const int* __restrict__ deg,
                                                      const float* __restrict__ biasb,
                                                      const float* __restrict__ biasa,
                                                      const int* __restrict__ crys,
                                                      float* __restrict__ pooled,
                                                      unsigned* __restrict__ done,
                                                      const float* __restrict__ fcW,
                                                      const float* __restrict__ fcb,
                                                      float* __restrict__ out) {
    const float* Y = blockIdx.y ? Ya : Yb;
    const float* bias = blockIdx.y ? biasa : biasb;
    const int cbase = blockIdx.y ? 64 : 0;
    const int wv = threadIdx.x >> 6, h = threadIdx.x & 63;
    int nodeA = blockIdx.x * 8 + wv * 2, nodeB = nodeA + 1;
    float oA, oB;
    agg_pair(Y, adj, deg, bias, nodeA, nodeB, h, oA, oB);
    int cA = 0, cB = 0;
#pragma unroll
    for (int t = 1; t < NCRYS; ++t) {
        int st = crys[t * 2];
        cA += (nodeA >= st) ? 1 : 0;
        cB += (nodeB >= st) ? 1 : 0;
    }
    int sub = blockIdx.x & (NSUB - 1);
    if (nodeA < NN) atomicAdd(&pooled[((size_t)cA * NSUB + sub) * 128 + cbase + h], oA);
    if (nodeB < NN) atomicAdd(&pooled[((size_t)cB * NSUB + sub) * 128 + cbase + h], oB);
    // ---- last block computes the final FC ----
    __threadfence();
    __shared__ unsigned lastFlag;
    if (threadIdx.x == 0)
        lastFlag = (atomicAdd(done, 1u) == 2u * 2500u - 1u) ? 1u : 0u;
    __syncthreads();
    if (lastFlag) {
        for (int q = wv; q < NCRYS * 2; q += 4) {
            int c = q >> 1, o = q & 1;
            float cnt = (float)(crys[c * 2 + 1] - crys[c * 2]);
            float sb = 0.f, sa = 0.f;
            for (int s = 0; s < NSUB; ++s) {
                sb += __hip_atomic_load(&pooled[((size_t)c * NSUB + s) * 128 + h],
                                        __ATOMIC_RELAXED, __HIP_MEMORY_SCOPE_AGENT);
                sa += __hip_atomic_load(&pooled[((size_t)c * NSUB + s) * 128 + 64 + h],
                                        __ATOMIC_RELAXED, __HIP_MEMORY_SCOPE_AGENT);
            }
            float a = sb * fcW[h * 2 + o] + sa * fcW[(64 + h) * 2 + o];
            for (int s = 32; s > 0; s >>= 1) a += __shfl_down(a, s);
            if (h == 0) out[c * 2 + o] = a / cnt + fcb[o];
        }
    }
}

extern "C" void kernel_launch(void* const* d_in, const int* in_sizes, int n_in,
                              void* d_out, int out_size, void* d_ws, size_t ws_size,
                              hipStream_t stream) {
    const float* bond    = (const float*)d_in[0];
    const float* angle   = (const float*)d_in[1];
    const int*   species = (const int*)d_in[2];
    const int*   nbr     = (const int*)d_in[3];
    const int*   crys    = (const int*)d_in[4];
    const float* W1b_rel = (const float*)d_in[5];
    const float* W1b_root= (const float*)d_in[6];
    const float* b1b     = (const float*)d_in[7];
    const float* W1a_rel = (const float*)d_in[8];
    const float* W1a_root= (const float*)d_in[9];
    const float* b1a     = (const float*)d_in[10];
    const float* W2b_rel = (const float*)d_in[11];
    const float* W2b_root= (const float*)d_in[12];
    const float* b2b     = (const float*)d_in[13];
    const float* W2a_rel = (const float*)d_in[14];
    const float* W2a_root= (const float*)d_in[15];
    const float* b2a     = (const float*)d_in[16];
    const float* fcW     = (const float*)d_in[17];
    const float* fcb     = (const float*)d_in[18];
    float* out = (float*)d_out;

    char* ws = (char*)d_ws;
    size_t off = 0;
    auto alloc = [&](size_t bytes) {
        char* p = ws + off;
        off = (off + bytes + 255) & ~(size_t)255;
        return p;
    };
    __bf16* Wp1b = (__bf16*)alloc((size_t)480 * 256 * 2);
    __bf16* Wp1a = (__bf16*)alloc((size_t)2880 * 256 * 2);
    __bf16* Wp2b = (__bf16*)alloc((size_t)64 * 256 * 2);
    __bf16* Wp2a = (__bf16*)alloc((size_t)64 * 256 * 2);
    float*  bondT = (float*)alloc((size_t)12 * NNP * 4);
    float*  angleT= (float*)alloc((size_t)144 * NNP * 4);
    float*  Yb   = (float*)alloc((size_t)NN * 256 * 4);
    float*  Ya   = (float*)alloc((size_t)NN * 256 * 4);
    float*  Y2b  = (float*)alloc((size_t)NN * 256 * 4);
    float*  Y2a  = (float*)alloc((size_t)NN * 256 * 4);
    int*    adj  = (int*)alloc((size_t)NN * 64 * 4);
    // zero-region: deg + pooled + done, contiguous, single memset
    char*   zbase = ws + off;
    int*    deg  = (int*)alloc((size_t)NN * 4);
    float*  pooled = (float*)alloc((size_t)NCRYS * NSUB * 128 * 4);
    unsigned* done = (unsigned*)alloc(256);
    size_t  zlen = (ws + off) - zbase;

    hipMemsetAsync(zbase, 0, zlen, stream);

    setup_kernel<<<1822, 256, 0, stream>>>(species, nbr, adj, deg,
                                           W1b_rel, W1b_root, W1a_rel, W1a_root,
                                           W2b_rel, W2b_root, W2a_rel, W2a_root,
                                           Wp1b, Wp1a, Wp2b, Wp2a,
                                           bond, angle, bondT, angleT);

    mega_gemm1<<<628, 512, 0, stream>>>(bondT, angleT, Wp1b, Wp1a, Yb, Ya);
    agg_gemm2<<<dim3(1256, 2), 256, 0, stream>>>(Yb, Ya, adj, deg, b1b, b1a,
                                                 Wp2b, Wp2a, Y2b, Y2a);
    agg_pool_final<<<dim3(2500, 2), 256, 0, stream>>>(Y2b, Y2a, adj, deg, b2b, b2a,
                                                      crys, pooled, done, fcW, fcb, out);
}

// Round 11
// 277.551 us; speedup vs baseline: 2.2453x; 2.2453x over previous
//
#include <hip/hip_runtime.h>

#define NN 20000
#define NNP 20096       // padded rows: 314*64
#define NEIGH 12
#define NCRYS 20
#define NSUB 16         // pooled partial-sum split

typedef __bf16 bf16x8 __attribute__((ext_vector_type(8)));
typedef __bf16 bf16x4 __attribute__((ext_vector_type(4)));
typedef float f32x4 __attribute__((ext_vector_type(4)));

// ============================================================
// pack: W[k][n] -> bf16 MFMA-B frag layout Wp[kt][nt][k8][ni][j]
// ============================================================
__device__ __forceinline__ void pack_one(const float* Wrel, const float* Wroot,
                                         __bf16* Wp, int K, int idx) {
    int k = idx >> 8, n = idx & 255;
    int r = n >> 6, h = n & 63;
    float v = (r < 3) ? Wrel[((size_t)r * K + k) * 64 + h] : Wroot[(size_t)k * 64 + h];
    int kt = k >> 5, k8 = (k >> 3) & 3, j = k & 7, nt = n >> 4, ni = n & 15;
    Wp[((((size_t)kt * 16 + nt) * 4 + k8) * 16 + ni) * 8 + j] = (__bf16)v;
}

// ============================================================
// setup: build_adj (938) + pack (256, strided) + transpose (628)
// ============================================================
__global__ __launch_bounds__(256) void setup_kernel(
    const int* __restrict__ species, const int* __restrict__ nbr,
    int* __restrict__ adj, int* __restrict__ deg,
    const float* __restrict__ W1b_rel, const float* __restrict__ W1b_root,
    const float* __restrict__ W1a_rel, const float* __restrict__ W1a_root,
    const float* __restrict__ W2b_rel, const float* __restrict__ W2b_root,
    const float* __restrict__ W2a_rel, const float* __restrict__ W2a_root,
    __bf16* __restrict__ Wp1b, __bf16* __restrict__ Wp1a,
    __bf16* __restrict__ Wp2b, __bf16* __restrict__ Wp2a,
    const float* __restrict__ bond, const float* __restrict__ angle,
    float* __restrict__ bondT, float* __restrict__ angleT) {
    __shared__ float ls[64 * 145];
    const int bx = blockIdx.x, tid = threadIdx.x;
    if (bx < 938) {
        int e = bx * 256 + tid;
        if (e < NN * NEIGH) {
            int i = e / NEIGH;
            int d = nbr[e];
            int r = species[i] + species[d];
            int slot = atomicAdd(&deg[d], 1);
            if (slot < 64) adj[(size_t)d * 64 + slot] = i | (r << 28);
        }
    } else if (bx < 938 + 256) {
        const int S0 = 480 * 256, S1 = S0 + 2880 * 256, S2 = S1 + 64 * 256, S3 = S2 + 64 * 256;
        for (int idx = (bx - 938) * 256 + tid; idx < S3; idx += 256 * 256) {
            if (idx < S0)       pack_one(W1b_rel, W1b_root, Wp1b, 480, idx);
            else if (idx < S1)  pack_one(W1a_rel, W1a_root, Wp1a, 2880, idx - S0);
            else if (idx < S2)  pack_one(W2b_rel, W2b_root, Wp2b, 64, idx - S1);
            else                pack_one(W2a_rel, W2a_root, Wp2a, 64, idx - S2);
        }
    } else {
        int tb = bx - 1194;
        if (tb < 314) {
            int m0 = tb * 64;
            for (int idx = tid; idx < 64 * 144; idx += 256) {
                int mm = idx / 144, j = idx - mm * 144;
                int m = m0 + mm;
                ls[mm * 145 + j] = (m < NN) ? angle[(size_t)m * 144 + j] : 0.f;
            }
            __syncthreads();
            for (int idx = tid; idx < 144 * 64; idx += 256) {
                int j = idx >> 6, mm = idx & 63;
                angleT[(size_t)j * NNP + m0 + mm] = ls[mm * 145 + j];
            }
        } else {
            int m0 = (tb - 314) * 64;
            for (int idx = tid; idx < 64 * 12; idx += 256) {
                int mm = idx / 12, j = idx - mm * 12;
                int m = m0 + mm;
                ls[mm * 13 + j] = (m < NN) ? bond[(size_t)m * 12 + j] : 0.f;
            }
            __syncthreads();
            for (int idx = tid; idx < 12 * 64; idx += 256) {
                int j = idx >> 6, mm = idx & 63;
                bondT[(size_t)j * NNP + m0 + mm] = ls[mm * 13 + j];
            }
        }
    }
}

// ============================================================
// gemm1 (R7/R9 structure, proven 53 us): 64x256 tile, 512 threads.
// ============================================================
template <int MODE>  // 0: bond K=480 DIVN=40; 1: angle K=2880 DIVN=20
__device__ __forceinline__ void gemm1_body(const float* __restrict__ xT,
                                           const __bf16* __restrict__ Wp,
                                           float* __restrict__ Y, int mb,
                                           __bf16* __restrict__ Al) {
    constexpr int KTOT = (MODE == 0) ? 480 : 2880;
    constexpr int NKT = KTOT / 32;
    constexpr int DIVN = (MODE == 0) ? 40 : 20;
    constexpr float F0 = (MODE == 0) ? 0.f : -1.f;
    constexpr float FS = (MODE == 0) ? (8.f / 39.f) : (2.f / 19.f);
    constexpr float NG2 = ((MODE == 0) ? -25.f : -100.f) * 1.44269504f;
    const float C  = __builtin_amdgcn_exp2f(2.f * NG2 * FS * FS);
    const float P1 = NG2 * FS * FS;
    const float P2 = -2.f * NG2 * FS;

    const int tid = threadIdx.x;
    const int lane = tid & 63, wv = tid >> 6;
    const int m0 = mb * 64;
    const int smt = tid >> 7;
    const int sk8 = (tid >> 5) & 3;
    const int smi = (tid >> 1) & 15;
    const int sjh = (tid & 1) * 4;
    const int sgm = m0 + smt * 16 + smi;
    const int kk0 = sk8 * 8 + sjh;
    const int swoff = (((smt * 4 + sk8) * 16 + smi) * 8 + sjh);
    const int k8b = lane >> 4, nib = lane & 15;
    const bf16x8* Bg = (const bf16x8*)Wp;

    f32x4 acc[4][2] = {};
    bf16x8 bcur[2], bnx[2], bnx2[2];

    auto bload = [&](int kt, bf16x8* d) {
#pragma unroll
        for (int jf = 0; jf < 2; ++jf)
            d[jf] = Bg[(((size_t)kt * 16 + 2 * wv + jf) * 4 + k8b) * 16 + nib];
    };
    auto aload = [&](int kt) -> float {
        int k = kt * 32 + kk0;
        int jr = k / DIVN;
        return xT[(size_t)jr * NNP + sgm];
    };
    auto stage = [&](int kt, float a, __bf16* dst) {
        int k = kt * 32 + kk0;
        int jr = k / DIVN;
        int s = k - jr * DIVN;
        float d0 = a - (F0 + (float)s * FS);
        float e0 = __builtin_amdgcn_exp2f(NG2 * d0 * d0);
        float q0 = __builtin_amdgcn_exp2f(fmaf(P2, d0, P1));
        float e1 = e0 * q0;
        float q1 = q0 * C;
        float e2 = e1 * q1;
        float e3 = e2 * q1 * C;
        bf16x4 vals;
        vals[0] = (__bf16)e0; vals[1] = (__bf16)e1;
        vals[2] = (__bf16)e2; vals[3] = (__bf16)e3;
        *(bf16x4*)&dst[swoff] = vals;
    };

    {
        float a0 = aload(0);
        stage(0, a0, Al);
    }
    float anext = aload(1 < NKT ? 1 : 0);
    bload(0, bcur);
    bload(1 < NKT ? 1 : 0, bnx);
    __syncthreads();

    for (int kt = 0; kt < NKT; ++kt) {
        __bf16* Ab = Al + ((kt & 1) << 11);
        __bf16* An = Al + (((kt & 1) ^ 1) << 11);
        const int ktp2 = (kt + 2 < NKT) ? kt + 2 : NKT - 1;
        bload(ktp2, bnx2);
        float afut = (kt + 2 < NKT) ? aload(kt + 2) : anext;
        bf16x8 af[4];
#pragma unroll
        for (int t = 0; t < 4; ++t)
            af[t] = *(const bf16x8*)&Ab[((((t << 2) + k8b) << 4) + nib) << 3];
#pragma unroll
        for (int i = 0; i < 4; ++i)
#pragma unroll
            for (int j = 0; j < 2; ++j)
                acc[i][j] = __builtin_amdgcn_mfma_f32_16x16x32_bf16(af[i], bcur[j], acc[i][j], 0, 0, 0);
        if (kt + 1 < NKT)
            stage(kt + 1, anext, An);
        __syncthreads();
#pragma unroll
        for (int j = 0; j < 2; ++j) { bcur[j] = bnx[j]; bnx[j] = bnx2[j]; }
        anext = afut;
    }

    const int mrow0 = m0 + ((lane >> 4) << 2);
    const int ncol = (wv << 5) + nib;
#pragma unroll
    for (int i = 0; i < 4; ++i)
#pragma unroll
        for (int j = 0; j < 2; ++j)
#pragma unroll
            for (int v = 0; v < 4; ++v) {
                int m = mrow0 + i * 16 + v;
                if (m < NN) Y[(size_t)m * 256 + ncol + j * 16] = acc[i][j][v];
            }
}

__global__ __launch_bounds__(512, 4) void mega_gemm1(const float* __restrict__ bondT,
                                                     const float* __restrict__ angleT,
                                                     const __bf16* __restrict__ Wp1b,
                                                     const __bf16* __restrict__ Wp1a,
                                                     float* __restrict__ Yb, float* __restrict__ Ya) {
    __shared__ __align__(16) __bf16 Al[2 * 2048];
    int bx = blockIdx.x;
    if (bx < 314) gemm1_body<1>(angleT, Wp1a, Ya, bx, Al);
    else          gemm1_body<0>(bondT, Wp1b, Yb, bx - 314, Al);
}

// ============================================================
// agg pair core: two nodes per wave, batched gathers
// ============================================================
__device__ __forceinline__ void agg_pair(const float* __restrict__ Y,
                                         const int* __restrict__ adj,
                                         const int* __restrict__ deg,
                                         const float* __restrict__ bias,
                                         int nodeA, int nodeB, int h,
                                         float& oA, float& oB) {
    bool hasA = nodeA < NN, hasB = nodeB < NN;
    int dgA = hasA ? min(deg[nodeA], 64) : 0;
    int dgB = hasB ? min(deg[nodeB], 64) : 0;
    int eA = hasA ? adj[(size_t)nodeA * 64 + h] : 0;
    int eB = hasB ? adj[(size_t)nodeB * 64 + h] : 0;
    float rootA = hasA ? Y[(size_t)nodeA * 256 + 192 + h] : 0.f;
    float rootB = hasB ? Y[(size_t)nodeB * 256 + 192 + h] : 0.f;
    bool vA = h < dgA, vB = h < dgB;
    int rA = eA >> 28, rB = eB >> 28;
    int cA0 = __popcll(__ballot(vA && rA == 0));
    int cA1 = __popcll(__ballot(vA && rA == 1));
    int cA2 = __popcll(__ballot(vA && rA == 2));
    int cB0 = __popcll(__ballot(vB && rB == 0));
    int cB1 = __popcll(__ballot(vB && rB == 1));
    int cB2 = __popcll(__ballot(vB && rB == 2));
    int ecA = vA ? eA : 0;
    int ecB = vB ? eB : 0;
    float sA0 = 0.f, sA1 = 0.f, sA2 = 0.f, sB0 = 0.f, sB1 = 0.f, sB2 = 0.f;
    int maxdg = max(dgA, dgB);
    for (int k0 = 0; k0 < maxdg; k0 += 16) {
        float va[16], vb[16];
        int ea[16], eb[16];
        bool doA = k0 < dgA, doB = k0 < dgB;
        if (doA) {
#pragma unroll
            for (int i = 0; i < 16; ++i) {
                ea[i] = __builtin_amdgcn_readlane(ecA, k0 + i);
                va[i] = Y[(size_t)(ea[i] & 0x0FFFFFFF) * 256 + (ea[i] >> 28) * 64 + h];
            }
        }
        if (doB) {
#pragma unroll
            for (int i = 0; i < 16; ++i) {
                eb[i] = __builtin_amdgcn_readlane(ecB, k0 + i);
                vb[i] = Y[(size_t)(eb[i] & 0x0FFFFFFF) * 256 + (eb[i] >> 28) * 64 + h];
            }
        }
        if (doA) {
#pragma unroll
            for (int i = 0; i < 16; ++i) {
                if (k0 + i < dgA) {
                    int rr = ea[i] >> 28;
                    if (rr == 0) sA0 += va[i];
                    else if (rr == 1) sA1 += va[i];
                    else sA2 += va[i];
                }
            }
        }
        if (doB) {
#pragma unroll
            for (int i = 0; i < 16; ++i) {
                if (k0 + i < dgB) {
                    int rr = eb[i] >> 28;
                    if (rr == 0) sB0 += vb[i];
                    else if (rr == 1) sB1 += vb[i];
                    else sB2 += vb[i];
                }
            }
        }
    }
    float bh = bias[h];
    oA = hasA ? fmaxf(rootA + bh + sA0 / fmaxf((float)cA0, 1.f) +
                      sA1 / fmaxf((float)cA1, 1.f) + sA2 / fmaxf((float)cA2, 1.f), 0.f)
              : 0.f;
    oB = hasB ? fmaxf(rootB + bh + sB0 / fmaxf((float)cB0, 1.f) +
                      sB1 / fmaxf((float)cB1, 1.f) + sB2 / fmaxf((float)cB2, 1.f), 0.f)
              : 0.f;
}

// ============================================================
// agg1 + gemm2 fused: block = 16 nodes = one MFMA m-tile.
// ============================================================
__global__ __launch_bounds__(256) void agg_gemm2(const float* __restrict__ Yb,
                                                 const float* __restrict__ Ya,
                                                 const int* __restrict__ adj,
                                                 const int* __restrict__ deg,
                                                 const float* __restrict__ biasb,
                                                 const float* __restrict__ biasa,
                                                 const __bf16* __restrict__ Wp2b,
                                                 const __bf16* __restrict__ Wp2a,
                                                 float* __restrict__ Y2b,
                                                 float* __restrict__ Y2a) {
    const float* Y = blockIdx.y ? Ya : Yb;
    const float* bias = blockIdx.y ? biasa : biasb;
    const __bf16* Wp = blockIdx.y ? Wp2a : Wp2b;
    float* Y2 = blockIdx.y ? Y2a : Y2b;
    __shared__ __align__(16) __bf16 Hl[1024];  // [kt 2][k8 4][mi 16][j 8]
    const int wv = threadIdx.x >> 6, lane = threadIdx.x & 63;
    const int h = lane;
    const int base = blockIdx.x * 16;
    // B prefetch (independent of gathers; in flight across them)
    const int k8b = lane >> 4, nib = lane & 15;
    const bf16x8* Bg = (const bf16x8*)Wp;
    bf16x8 bfr[2][4];
#pragma unroll
    for (int kt = 0; kt < 2; ++kt)
#pragma unroll
        for (int t = 0; t < 4; ++t)
            bfr[kt][t] = Bg[(((size_t)kt * 16 + wv * 4 + t) * 4 + k8b) * 16 + nib];
    // gather 4 nodes per wave (2 pairs)
    const int hkt = h >> 5, hk8 = (h >> 3) & 3, hj = h & 7;
#pragma unroll
    for (int p = 0; p < 2; ++p) {
        int nodeA = base + wv * 4 + p * 2;
        int nodeB = nodeA + 1;
        float oA, oB;
        agg_pair(Y, adj, deg, bias, nodeA, nodeB, h, oA, oB);
        int mi = wv * 4 + p * 2;
        Hl[((hkt * 4 + hk8) * 16 + mi) * 8 + hj] = (__bf16)oA;
        Hl[((hkt * 4 + hk8) * 16 + mi + 1) * 8 + hj] = (__bf16)oB;
    }
    __syncthreads();
    // MFMA: 16 rows x 64 cols per wave
    bf16x8 af[2];
#pragma unroll
    for (int kt = 0; kt < 2; ++kt)
        af[kt] = *(const bf16x8*)&Hl[((kt * 4 + k8b) * 16 + nib) * 8];
    f32x4 acc[4] = {};
#pragma unroll
    for (int kt = 0; kt < 2; ++kt)
#pragma unroll
        for (int t = 0; t < 4; ++t)
            acc[t] = __builtin_amdgcn_mfma_f32_16x16x32_bf16(af[kt], bfr[kt][t], acc[t], 0, 0, 0);
    const int r0 = (lane >> 4) << 2;
    const int c0 = wv * 64 + nib;
#pragma unroll
    for (int t = 0; t < 4; ++t)
#pragma unroll
        for (int v = 0; v < 4; ++v) {
            int node = base + r0 + v;
            if (node < NN) Y2[(size_t)node * 256 + c0 + t * 16] = acc[t][v];
        }
}

// ============================================================
// agg2 + crystal pooling (no fence, no last-block — R9 proven)
// ============================================================
__global__ __launch_bounds__(256) void agg_pool(const float* __restrict__ Yb,
                                                const float* __restrict__ Ya,
                                                const int* __restrict__ adj,
                                                const int* __restrict__ deg,
                                                const float* __restrict__ biasb,
                                                const float* __restrict__ biasa,
                                                const int* __restrict__ crys,
                                                float* __restrict__ pooled) {
    const float* Y = blockIdx.y ? Ya : Yb;
    const float* bias = blockIdx.y ? biasa : biasb;
    const int cbase = blockIdx.y ? 64 : 0;
    const int wv = threadIdx.x >> 6, h = threadIdx.x & 63;
    int nodeA = blockIdx.x * 8 + wv * 2, nodeB = nodeA + 1;
    float oA, oB;
    agg_pair(Y, adj, deg, bias, nodeA, nodeB, h, oA, oB);
    int cA = 0, cB = 0;
#pragma unroll
    for (int t = 1; t < NCRYS; ++t) {
        int st = crys[t * 2];
        cA += (nodeA >= st) ? 1 : 0;
        cB += (nodeB >= st) ? 1 : 0;
    }
    int sub = blockIdx.x & (NSUB - 1);
    if (nodeA < NN) atomicAdd(&pooled[((size_t)cA * NSUB + sub) * 128 + cbase + h], oA);
    if (nodeB < NN) atomicAdd(&pooled[((size_t)cB * NSUB + sub) * 128 + cbase + h], oB);
}

// ============================================================
// final: reduce partials, divide by count, FC
// ============================================================
__global__ void final2(const float* __restrict__ pooled, const int* __restrict__ crys,
                       const float* __restrict__ fcW, const float* __restrict__ fcb,
                       float* __restrict__ out) {
    int c = blockIdx.x >> 1, o = blockIdx.x & 1;
    int l = threadIdx.x;  // 0..63
    float cnt = (float)(crys[c * 2 + 1] - crys[c * 2]);
    float sb = 0.f, sa = 0.f;
    for (int s = 0; s < NSUB; ++s) {
        sb += pooled[((size_t)c * NSUB + s) * 128 + l];
        sa += pooled[((size_t)c * NSUB + s) * 128 + 64 + l];
    }
    float a = sb * fcW[l * 2 + o] + sa * fcW[(64 + l) * 2 + o];
    for (int s = 32; s > 0; s >>= 1) a += __shfl_down(a, s);
    if (l == 0) out[c * 2 + o] = a / cnt + fcb[o];
}

extern "C" void kernel_launch(void* const* d_in, const int* in_sizes, int n_in,
                              void* d_out, int out_size, void* d_ws, size_t ws_size,
                              hipStream_t stream) {
    const float* bond    = (const float*)d_in[0];
    const float* angle   = (const float*)d_in[1];
    const int*   species = (const int*)d_in[2];
    const int*   nbr     = (const int*)d_in[3];
    const int*   crys    = (const int*)d_in[4];
    const float* W1b_rel = (const float*)d_in[5];
    const float* W1b_root= (const float*)d_in[6];
    const float* b1b     = (const float*)d_in[7];
    const float* W1a_rel = (const float*)d_in[8];
    const float* W1a_root= (const float*)d_in[9];
    const float* b1a     = (const float*)d_in[10];
    const float* W2b_rel = (const float*)d_in[11];
    const float* W2b_root= (const float*)d_in[12];
    const float* b2b     = (const float*)d_in[13];
    const float* W2a_rel = (const float*)d_in[14];
    const float* W2a_root= (const float*)d_in[15];
    const float* b2a     = (const float*)d_in[16];
    const float* fcW     = (const float*)d_in[17];
    const float* fcb     = (const float*)d_in[18];
    float* out = (float*)d_out;

    char* ws = (char*)d_ws;
    size_t off = 0;
    auto alloc = [&](size_t bytes) {
        char* p = ws + off;
        off = (off + bytes + 255) & ~(size_t)255;
        return p;
    };
    __bf16* Wp1b = (__bf16*)alloc((size_t)480 * 256 * 2);
    __bf16* Wp1a = (__bf16*)alloc((size_t)2880 * 256 * 2);
    __bf16* Wp2b = (__bf16*)alloc((size_t)64 * 256 * 2);
    __bf16* Wp2a = (__bf16*)alloc((size_t)64 * 256 * 2);
    float*  bondT = (float*)alloc((size_t)12 * NNP * 4);
    float*  angleT= (float*)alloc((size_t)144 * NNP * 4);
    float*  Yb   = (float*)alloc((size_t)NN * 256 * 4);
    float*  Ya   = (float*)alloc((size_t)NN * 256 * 4);
    float*  Y2b  = (float*)alloc((size_t)NN * 256 * 4);
    float*  Y2a  = (float*)alloc((size_t)NN * 256 * 4);
    int*    adj  = (int*)alloc((size_t)NN * 64 * 4);
    // zero-region: deg + pooled, contiguous, single memset
    char*   zbase = ws + off;
    int*    deg  = (int*)alloc((size_t)NN * 4);
    float*  pooled = (float*)alloc((size_t)NCRYS * NSUB * 128 * 4);
    size_t  zlen = (ws + off) - zbase;

    hipMemsetAsync(zbase, 0, zlen, stream);

    setup_kernel<<<1822, 256, 0, stream>>>(species, nbr, adj, deg,
                                           W1b_rel, W1b_root, W1a_rel, W1a_root,
                                           W2b_rel, W2b_root, W2a_rel, W2a_root,
                                           Wp1b, Wp1a, Wp2b, Wp2a,
                                           bond, angle, bondT, angleT);

    mega_gemm1<<<628, 512, 0, stream>>>(bondT, angleT, Wp1b, Wp1a, Yb, Ya);
    agg_gemm2<<<dim3(1256, 2), 256, 0, stream>>>(Yb, Ya, adj, deg, b1b, b1a,
                                                 Wp2b, Wp2a, Y2b, Y2a);
    agg_pool<<<dim3(2500, 2), 256, 0, stream>>>(Y2b, Y2a, adj, deg, b2b, b2a,
                                                crys, pooled);
    final2<<<NCRYS * 2, 64, 0, stream>>>(pooled, crys, fcW, fcb, out);
}

// Round 12
// 272.555 us; speedup vs baseline: 2.2865x; 1.0183x over previous
//
#include <hip/hip_runtime.h>

#define NN 20000
#define NNP 20096       // padded rows: 314*64
#define NEIGH 12
#define NCRYS 20
#define NSUB 16         // pooled partial-sum split

typedef __bf16 bf16x8 __attribute__((ext_vector_type(8)));
typedef __bf16 bf16x4 __attribute__((ext_vector_type(4)));
typedef float f32x4 __attribute__((ext_vector_type(4)));

// ============================================================
// pack: W[k][n] -> bf16 MFMA-B frag layout Wp[kt][nt][k8][ni][j]
// ============================================================
__device__ __forceinline__ void pack_one(const float* Wrel, const float* Wroot,
                                         __bf16* Wp, int K, int idx) {
    int k = idx >> 8, n = idx & 255;
    int r = n >> 6, h = n & 63;
    float v = (r < 3) ? Wrel[((size_t)r * K + k) * 64 + h] : Wroot[(size_t)k * 64 + h];
    int kt = k >> 5, k8 = (k >> 3) & 3, j = k & 7, nt = n >> 4, ni = n & 15;
    Wp[((((size_t)kt * 16 + nt) * 4 + k8) * 16 + ni) * 8 + j] = (__bf16)v;
}

// ============================================================
// setup: build_adj (938) + pack (256, strided) + transpose (628)
// ============================================================
__global__ __launch_bounds__(256) void setup_kernel(
    const int* __restrict__ species, const int* __restrict__ nbr,
    int* __restrict__ adj, int* __restrict__ deg,
    const float* __restrict__ W1b_rel, const float* __restrict__ W1b_root,
    const float* __restrict__ W1a_rel, const float* __restrict__ W1a_root,
    const float* __restrict__ W2b_rel, const float* __restrict__ W2b_root,
    const float* __restrict__ W2a_rel, const float* __restrict__ W2a_root,
    __bf16* __restrict__ Wp1b, __bf16* __restrict__ Wp1a,
    __bf16* __restrict__ Wp2b, __bf16* __restrict__ Wp2a,
    const float* __restrict__ bond, const float* __restrict__ angle,
    float* __restrict__ bondT, float* __restrict__ angleT) {
    __shared__ float ls[64 * 145];
    const int bx = blockIdx.x, tid = threadIdx.x;
    if (bx < 938) {
        int e = bx * 256 + tid;
        if (e < NN * NEIGH) {
            int i = e / NEIGH;
            int d = nbr[e];
            int r = species[i] + species[d];
            int slot = atomicAdd(&deg[d], 1);
            if (slot < 64) adj[(size_t)d * 64 + slot] = i | (r << 28);
        }
    } else if (bx < 938 + 256) {
        const int S0 = 480 * 256, S1 = S0 + 2880 * 256, S2 = S1 + 64 * 256, S3 = S2 + 64 * 256;
        for (int idx = (bx - 938) * 256 + tid; idx < S3; idx += 256 * 256) {
            if (idx < S0)       pack_one(W1b_rel, W1b_root, Wp1b, 480, idx);
            else if (idx < S1)  pack_one(W1a_rel, W1a_root, Wp1a, 2880, idx - S0);
            else if (idx < S2)  pack_one(W2b_rel, W2b_root, Wp2b, 64, idx - S1);
            else                pack_one(W2a_rel, W2a_root, Wp2a, 64, idx - S2);
        }
    } else {
        int tb = bx - 1194;
        if (tb < 314) {
            int m0 = tb * 64;
            for (int idx = tid; idx < 64 * 144; idx += 256) {
                int mm = idx / 144, j = idx - mm * 144;
                int m = m0 + mm;
                ls[mm * 145 + j] = (m < NN) ? angle[(size_t)m * 144 + j] : 0.f;
            }
            __syncthreads();
            for (int idx = tid; idx < 144 * 64; idx += 256) {
                int j = idx >> 6, mm = idx & 63;
                angleT[(size_t)j * NNP + m0 + mm] = ls[mm * 145 + j];
            }
        } else {
            int m0 = (tb - 314) * 64;
            for (int idx = tid; idx < 64 * 12; idx += 256) {
                int mm = idx / 12, j = idx - mm * 12;
                int m = m0 + mm;
                ls[mm * 13 + j] = (m < NN) ? bond[(size_t)m * 12 + j] : 0.f;
            }
            __syncthreads();
            for (int idx = tid; idx < 12 * 64; idx += 256) {
                int j = idx >> 6, mm = idx & 63;
                bondT[(size_t)j * NNP + m0 + mm] = ls[mm * 13 + j];
            }
        }
    }
}

// ============================================================
// compact-Y epilogue helper:
//  col c>=192        -> Yroot[m][c-192] (f32)
//  c in [ss*64, +128)-> Ysel[m][c-ss*64] (bf16) — the only rel cols ever
//                       gathered for this node (r = ss_src + sd_dst)
// ============================================================
__device__ __forceinline__ void epi_write(float* __restrict__ Yroot,
                                          __bf16* __restrict__ Ysel,
                                          int m, int c, int ss, float v) {
    if (c >= 192) {
        Yroot[(size_t)m * 64 + (c - 192)] = v;
    } else {
        int rc = c - (ss << 6);
        if ((unsigned)rc < 128u) Ysel[(size_t)m * 128 + rc] = (__bf16)v;
    }
}

// ============================================================
// gemm1 (R7/R9 K-loop, proven): 64x256 tile, 512 threads; compact-Y epilogue
// ============================================================
template <int MODE>  // 0: bond K=480 DIVN=40; 1: angle K=2880 DIVN=20
__device__ __forceinline__ void gemm1_body(const float* __restrict__ xT,
                                           const __bf16* __restrict__ Wp,
                                           const int* __restrict__ species,
                                           float* __restrict__ Yroot,
                                           __bf16* __restrict__ Ysel, int mb,
                                           __bf16* __restrict__ Al) {
    constexpr int KTOT = (MODE == 0) ? 480 : 2880;
    constexpr int NKT = KTOT / 32;
    constexpr int DIVN = (MODE == 0) ? 40 : 20;
    constexpr float F0 = (MODE == 0) ? 0.f : -1.f;
    constexpr float FS = (MODE == 0) ? (8.f / 39.f) : (2.f / 19.f);
    constexpr float NG2 = ((MODE == 0) ? -25.f : -100.f) * 1.44269504f;
    const float C  = __builtin_amdgcn_exp2f(2.f * NG2 * FS * FS);
    const float P1 = NG2 * FS * FS;
    const float P2 = -2.f * NG2 * FS;

    const int tid = threadIdx.x;
    const int lane = tid & 63, wv = tid >> 6;
    const int m0 = mb * 64;
    const int smt = tid >> 7;
    const int sk8 = (tid >> 5) & 3;
    const int smi = (tid >> 1) & 15;
    const int sjh = (tid & 1) * 4;
    const int sgm = m0 + smt * 16 + smi;
    const int kk0 = sk8 * 8 + sjh;
    const int swoff = (((smt * 4 + sk8) * 16 + smi) * 8 + sjh);
    const int k8b = lane >> 4, nib = lane & 15;
    const bf16x8* Bg = (const bf16x8*)Wp;

    f32x4 acc[4][2] = {};
    bf16x8 bcur[2], bnx[2], bnx2[2];

    auto bload = [&](int kt, bf16x8* d) {
#pragma unroll
        for (int jf = 0; jf < 2; ++jf)
            d[jf] = Bg[(((size_t)kt * 16 + 2 * wv + jf) * 4 + k8b) * 16 + nib];
    };
    auto aload = [&](int kt) -> float {
        int k = kt * 32 + kk0;
        int jr = k / DIVN;
        return xT[(size_t)jr * NNP + sgm];
    };
    auto stage = [&](int kt, float a, __bf16* dst) {
        int k = kt * 32 + kk0;
        int jr = k / DIVN;
        int s = k - jr * DIVN;
        float d0 = a - (F0 + (float)s * FS);
        float e0 = __builtin_amdgcn_exp2f(NG2 * d0 * d0);
        float q0 = __builtin_amdgcn_exp2f(fmaf(P2, d0, P1));
        float e1 = e0 * q0;
        float q1 = q0 * C;
        float e2 = e1 * q1;
        float e3 = e2 * q1 * C;
        bf16x4 vals;
        vals[0] = (__bf16)e0; vals[1] = (__bf16)e1;
        vals[2] = (__bf16)e2; vals[3] = (__bf16)e3;
        *(bf16x4*)&dst[swoff] = vals;
    };

    {
        float a0 = aload(0);
        stage(0, a0, Al);
    }
    float anext = aload(1 < NKT ? 1 : 0);
    bload(0, bcur);
    bload(1 < NKT ? 1 : 0, bnx);
    __syncthreads();

    for (int kt = 0; kt < NKT; ++kt) {
        __bf16* Ab = Al + ((kt & 1) << 11);
        __bf16* An = Al + (((kt & 1) ^ 1) << 11);
        const int ktp2 = (kt + 2 < NKT) ? kt + 2 : NKT - 1;
        bload(ktp2, bnx2);
        float afut = (kt + 2 < NKT) ? aload(kt + 2) : anext;
        bf16x8 af[4];
#pragma unroll
        for (int t = 0; t < 4; ++t)
            af[t] = *(const bf16x8*)&Ab[((((t << 2) + k8b) << 4) + nib) << 3];
#pragma unroll
        for (int i = 0; i < 4; ++i)
#pragma unroll
            for (int j = 0; j < 2; ++j)
                acc[i][j] = __builtin_amdgcn_mfma_f32_16x16x32_bf16(af[i], bcur[j], acc[i][j], 0, 0, 0);
        if (kt + 1 < NKT)
            stage(kt + 1, anext, An);
        __syncthreads();
#pragma unroll
        for (int j = 0; j < 2; ++j) { bcur[j] = bnx[j]; bnx[j] = bnx2[j]; }
        anext = afut;
    }

    // ---- stage species for the 64 rows (reuse LDS) ----
    int* specLS = (int*)Al;
    if (tid < 64) specLS[tid] = (m0 + tid < NN) ? species[m0 + tid] : 0;
    __syncthreads();

    // ---- compact-Y epilogue: C/D layout col=lane&15, row=(lane>>4)*4+reg ----
    const int mrow0 = m0 + ((lane >> 4) << 2);
    const int ncol = (wv << 5) + nib;
#pragma unroll
    for (int i = 0; i < 4; ++i)
#pragma unroll
        for (int j = 0; j < 2; ++j)
#pragma unroll
            for (int v = 0; v < 4; ++v) {
                int m = mrow0 + i * 16 + v;
                if (m < NN)
                    epi_write(Yroot, Ysel, m, ncol + j * 16, specLS[m - m0], acc[i][j][v]);
            }
}

__global__ __launch_bounds__(512, 4) void mega_gemm1(const float* __restrict__ bondT,
                                                     const float* __restrict__ angleT,
                                                     const int* __restrict__ species,
                                                     const __bf16* __restrict__ Wp1b,
                                                     const __bf16* __restrict__ Wp1a,
                                                     float* __restrict__ Yrb, __bf16* __restrict__ Ysb,
                                                     float* __restrict__ Yra, __bf16* __restrict__ Ysa) {
    __shared__ __align__(16) __bf16 Al[2 * 2048];
    int bx = blockIdx.x;
    if (bx < 314) gemm1_body<1>(angleT, Wp1a, species, Yra, Ysa, bx, Al);
    else          gemm1_body<0>(bondT, Wp1b, species, Yrb, Ysb, bx - 314, Al);
}

// ============================================================
// agg pair core on compact Y: gathers 128B bf16 rows from the 5MB
// L2-resident Ysel table; block offset sd*64 is wave-uniform.
// ============================================================
__device__ __forceinline__ void agg_pair(const __bf16* __restrict__ Ysel,
                                         const float* __restrict__ Yroot,
                                         const int* __restrict__ adj,
                                         const int* __restrict__ deg,
                                         const float* __restrict__ bias,
                                         int nodeA, int nodeB, int sdA, int sdB, int h,
                                         float& oA, float& oB) {
    bool hasA = nodeA < NN, hasB = nodeB < NN;
    int dgA = hasA ? min(deg[nodeA], 64) : 0;
    int dgB = hasB ? min(deg[nodeB], 64) : 0;
    int eA = hasA ? adj[(size_t)nodeA * 64 + h] : 0;
    int eB = hasB ? adj[(size_t)nodeB * 64 + h] : 0;
    float rootA = hasA ? Yroot[(size_t)nodeA * 64 + h] : 0.f;
    float rootB = hasB ? Yroot[(size_t)nodeB * 64 + h] : 0.f;
    bool vA = h < dgA, vB = h < dgB;
    int rA = eA >> 28, rB = eB >> 28;
    int cA0 = __popcll(__ballot(vA && rA == 0));
    int cA1 = __popcll(__ballot(vA && rA == 1));
    int cA2 = __popcll(__ballot(vA && rA == 2));
    int cB0 = __popcll(__ballot(vB && rB == 0));
    int cB1 = __popcll(__ballot(vB && rB == 1));
    int cB2 = __popcll(__ballot(vB && rB == 2));
    int ecA = vA ? eA : 0;
    int ecB = vB ? eB : 0;
    const int offA = sdA * 64 + h, offB = sdB * 64 + h;
    float sA0 = 0.f, sA1 = 0.f, sA2 = 0.f, sB0 = 0.f, sB1 = 0.f, sB2 = 0.f;
    int maxdg = max(dgA, dgB);
    for (int k0 = 0; k0 < maxdg; k0 += 16) {
        float va[16], vb[16];
        int ea[16], eb[16];
        bool doA = k0 < dgA, doB = k0 < dgB;
        if (doA) {
#pragma unroll
            for (int i = 0; i < 16; ++i) {
                ea[i] = __builtin_amdgcn_readlane(ecA, k0 + i);
                va[i] = (float)Ysel[(size_t)(ea[i] & 0x0FFFFFFF) * 128 + offA];
            }
        }
        if (doB) {
#pragma unroll
            for (int i = 0; i < 16; ++i) {
                eb[i] = __builtin_amdgcn_readlane(ecB, k0 + i);
                vb[i] = (float)Ysel[(size_t)(eb[i] & 0x0FFFFFFF) * 128 + offB];
            }
        }
        if (doA) {
#pragma unroll
            for (int i = 0; i < 16; ++i) {
                if (k0 + i < dgA) {
                    int rr = ea[i] >> 28;
                    if (rr == 0) sA0 += va[i];
                    else if (rr == 1) sA1 += va[i];
                    else sA2 += va[i];
                }
            }
        }
        if (doB) {
#pragma unroll
            for (int i = 0; i < 16; ++i) {
                if (k0 + i < dgB) {
                    int rr = eb[i] >> 28;
                    if (rr == 0) sB0 += vb[i];
                    else if (rr == 1) sB1 += vb[i];
                    else sB2 += vb[i];
                }
            }
        }
    }
    float bh = bias[h];
    oA = hasA ? fmaxf(rootA + bh + sA0 / fmaxf((float)cA0, 1.f) +
                      sA1 / fmaxf((float)cA1, 1.f) + sA2 / fmaxf((float)cA2, 1.f), 0.f)
              : 0.f;
    oB = hasB ? fmaxf(rootB + bh + sB0 / fmaxf((float)cB0, 1.f) +
                      sB1 / fmaxf((float)cB1, 1.f) + sB2 / fmaxf((float)cB2, 1.f), 0.f)
              : 0.f;
}

// ============================================================
// agg1 + gemm2 fused, compact-Y in AND out. Block = 16 nodes = one m-tile.
// ============================================================
__global__ __launch_bounds__(256) void agg_gemm2(const __bf16* __restrict__ Ysb,
                                                 const float* __restrict__ Yrb,
                                                 const __bf16* __restrict__ Ysa,
                                                 const float* __restrict__ Yra,
                                                 const int* __restrict__ species,
                                                 const int* __restrict__ adj,
                                                 const int* __restrict__ deg,
                                                 const float* __restrict__ biasb,
                                                 const float* __restrict__ biasa,
                                                 const __bf16* __restrict__ Wp2b,
                                                 const __bf16* __restrict__ Wp2a,
                                                 float* __restrict__ Y2rb, __bf16* __restrict__ Y2sb,
                                                 float* __restrict__ Y2ra, __bf16* __restrict__ Y2sa) {
    const __bf16* Ysel = blockIdx.y ? Ysa : Ysb;
    const float* Yroot = blockIdx.y ? Yra : Yrb;
    const float* bias = blockIdx.y ? biasa : biasb;
    const __bf16* Wp = blockIdx.y ? Wp2a : Wp2b;
    float* Y2root = blockIdx.y ? Y2ra : Y2rb;
    __bf16* Y2sel = blockIdx.y ? Y2sa : Y2sb;
    __shared__ __align__(16) __bf16 Hl[1024];  // [kt 2][k8 4][mi 16][j 8]
    __shared__ int specLS[16];
    const int wv = threadIdx.x >> 6, lane = threadIdx.x & 63;
    const int h = lane;
    const int base = blockIdx.x * 16;
    if (threadIdx.x < 16)
        specLS[threadIdx.x] = (base + threadIdx.x < NN) ? species[base + threadIdx.x] : 0;
    // B prefetch (in flight across the gathers)
    const int k8b = lane >> 4, nib = lane & 15;
    const bf16x8* Bg = (const bf16x8*)Wp;
    bf16x8 bfr[2][4];
#pragma unroll
    for (int kt = 0; kt < 2; ++kt)
#pragma unroll
        for (int t = 0; t < 4; ++t)
            bfr[kt][t] = Bg[(((size_t)kt * 16 + wv * 4 + t) * 4 + k8b) * 16 + nib];
    __syncthreads();
    // gather 4 nodes per wave (2 pairs)
    const int hkt = h >> 5, hk8 = (h >> 3) & 3, hj = h & 7;
#pragma unroll
    for (int p = 0; p < 2; ++p) {
        int mi = wv * 4 + p * 2;
        int nodeA = base + mi;
        int nodeB = nodeA + 1;
        float oA, oB;
        agg_pair(Ysel, Yroot, adj, deg, bias, nodeA, nodeB,
                 specLS[mi], specLS[mi + 1], h, oA, oB);
        Hl[((hkt * 4 + hk8) * 16 + mi) * 8 + hj] = (__bf16)oA;
        Hl[((hkt * 4 + hk8) * 16 + mi + 1) * 8 + hj] = (__bf16)oB;
    }
    __syncthreads();
    // MFMA: 16 rows x 64 cols per wave
    bf16x8 af[2];
#pragma unroll
    for (int kt = 0; kt < 2; ++kt)
        af[kt] = *(const bf16x8*)&Hl[((kt * 4 + k8b) * 16 + nib) * 8];
    f32x4 acc[4] = {};
#pragma unroll
    for (int kt = 0; kt < 2; ++kt)
#pragma unroll
        for (int t = 0; t < 4; ++t)
            acc[t] = __builtin_amdgcn_mfma_f32_16x16x32_bf16(af[kt], bfr[kt][t], acc[t], 0, 0, 0);
    // compact-Y epilogue: row=(lane>>4)*4+v, col=wv*64+t*16+nib
    const int r0 = (lane >> 4) << 2;
    const int c0 = wv * 64 + nib;
#pragma unroll
    for (int t = 0; t < 4; ++t)
#pragma unroll
        for (int v = 0; v < 4; ++v) {
            int node = base + r0 + v;
            if (node < NN)
                epi_write(Y2root, Y2sel, node, c0 + t * 16, specLS[r0 + v], acc[t][v]);
        }
}

// ============================================================
// agg2 + crystal pooling on compact Y2
// ============================================================
__global__ __launch_bounds__(256) void agg_pool(const __bf16* __restrict__ Y2sb,
                                                const float* __restrict__ Y2rb,
                                                const __bf16* __restrict__ Y2sa,
                                                const float* __restrict__ Y2ra,
                                                const int* __restrict__ species,
                                                const int* __restrict__ adj,
                                                const int* __restrict__ deg,
                                                const float* __restrict__ biasb,
                                                const float* __restrict__ biasa,
                                                const int* __restrict__ crys,
                                                float* __restrict__ pooled) {
    const __bf16* Ysel = blockIdx.y ? Y2sa : Y2sb;
    const float* Yroot = blockIdx.y ? Y2ra : Y2rb;
    const float* bias = blockIdx.y ? biasa : biasb;
    const int cbase = blockIdx.y ? 64 : 0;
    const int wv = threadIdx.x >> 6, h = threadIdx.x & 63;
    int nodeA = blockIdx.x * 8 + wv * 2, nodeB = nodeA + 1;
    int sdA = (nodeA < NN) ? species[nodeA] : 0;
    int sdB = (nodeB < NN) ? species[nodeB] : 0;
    float oA, oB;
    agg_pair(Ysel, Yroot, adj, deg, bias, nodeA, nodeB, sdA, sdB, h, oA, oB);
    int cA = 0, cB = 0;
#pragma unroll
    for (int t = 1; t < NCRYS; ++t) {
        int st = crys[t * 2];
        cA += (nodeA >= st) ? 1 : 0;
        cB += (nodeB >= st) ? 1 : 0;
    }
    int sub = blockIdx.x & (NSUB - 1);
    if (nodeA < NN) atomicAdd(&pooled[((size_t)cA * NSUB + sub) * 128 + cbase + h], oA);
    if (nodeB < NN) atomicAdd(&pooled[((size_t)cB * NSUB + sub) * 128 + cbase + h], oB);
}

// ============================================================
// final: reduce partials, divide by count, FC
// ============================================================
__global__ void final2(const float* __restrict__ pooled, const int* __restrict__ crys,
                       const float* __restrict__ fcW, const float* __restrict__ fcb,
                       float* __restrict__ out) {
    int c = blockIdx.x >> 1, o = blockIdx.x & 1;
    int l = threadIdx.x;  // 0..63
    float cnt = (float)(crys[c * 2 + 1] - crys[c * 2]);
    float sb = 0.f, sa = 0.f;
    for (int s = 0; s < NSUB; ++s) {
        sb += pooled[((size_t)c * NSUB + s) * 128 + l];
        sa += pooled[((size_t)c * NSUB + s) * 128 + 64 + l];
    }
    float a = sb * fcW[l * 2 + o] + sa * fcW[(64 + l) * 2 + o];
    for (int s = 32; s > 0; s >>= 1) a += __shfl_down(a, s);
    if (l == 0) out[c * 2 + o] = a / cnt + fcb[o];
}

extern "C" void kernel_launch(void* const* d_in, const int* in_sizes, int n_in,
                              void* d_out, int out_size, void* d_ws, size_t ws_size,
                              hipStream_t stream) {
    const float* bond    = (const float*)d_in[0];
    const float* angle   = (const float*)d_in[1];
    const int*   species = (const int*)d_in[2];
    const int*   nbr     = (const int*)d_in[3];
    const int*   crys    = (const int*)d_in[4];
    const float* W1b_rel = (const float*)d_in[5];
    const float* W1b_root= (const float*)d_in[6];
    const float* b1b     = (const float*)d_in[7];
    const float* W1a_rel = (const float*)d_in[8];
    const float* W1a_root= (const float*)d_in[9];
    const float* b1a     = (const float*)d_in[10];
    const float* W2b_rel = (const float*)d_in[11];
    const float* W2b_root= (const float*)d_in[12];
    const float* b2b     = (const float*)d_in[13];
    const float* W2a_rel = (const float*)d_in[14];
    const float* W2a_root= (const float*)d_in[15];
    const float* b2a     = (const float*)d_in[16];
    const float* fcW     = (const float*)d_in[17];
    const float* fcb     = (const float*)d_in[18];
    float* out = (float*)d_out;

    char* ws = (char*)d_ws;
    size_t off = 0;
    auto alloc = [&](size_t bytes) {
        char* p = ws + off;
        off = (off + bytes + 255) & ~(size_t)255;
        return p;
    };
    __bf16* Wp1b = (__bf16*)alloc((size_t)480 * 256 * 2);
    __bf16* Wp1a = (__bf16*)alloc((size_t)2880 * 256 * 2);
    __bf16* Wp2b = (__bf16*)alloc((size_t)64 * 256 * 2);
    __bf16* Wp2a = (__bf16*)alloc((size_t)64 * 256 * 2);
    float*  bondT = (float*)alloc((size_t)12 * NNP * 4);
    float*  angleT= (float*)alloc((size_t)144 * NNP * 4);
    float*  Yrb  = (float*)alloc((size_t)NN * 64 * 4);
    float*  Yra  = (float*)alloc((size_t)NN * 64 * 4);
    __bf16* Ysb  = (__bf16*)alloc((size_t)NN * 128 * 2);
    __bf16* Ysa  = (__bf16*)alloc((size_t)NN * 128 * 2);
    float*  Y2rb = (float*)alloc((size_t)NN * 64 * 4);
    float*  Y2ra = (float*)alloc((size_t)NN * 64 * 4);
    __bf16* Y2sb = (__bf16*)alloc((size_t)NN * 128 * 2);
    __bf16* Y2sa = (__bf16*)alloc((size_t)NN * 128 * 2);
    int*    adj  = (int*)alloc((size_t)NN * 64 * 4);
    // zero-region: deg + pooled, single memset
    char*   zbase = ws + off;
    int*    deg  = (int*)alloc((size_t)NN * 4);
    float*  pooled = (float*)alloc((size_t)NCRYS * NSUB * 128 * 4);
    size_t  zlen = (ws + off) - zbase;

    hipMemsetAsync(zbase, 0, zlen, stream);

    setup_kernel<<<1822, 256, 0, stream>>>(species, nbr, adj, deg,
                                           W1b_rel, W1b_root, W1a_rel, W1a_root,
                                           W2b_rel, W2b_root, W2a_rel, W2a_root,
                                           Wp1b, Wp1a, Wp2b, Wp2a,
                                           bond, angle, bondT, angleT);

    mega_gemm1<<<628, 512, 0, stream>>>(bondT, angleT, species, Wp1b, Wp1a,
                                        Yrb, Ysb, Yra, Ysa);
    agg_gemm2<<<dim3(1256, 2), 256, 0, stream>>>(Ysb, Yrb, Ysa, Yra, species,
                                                 adj, deg, b1b, b1a, Wp2b, Wp2a,
                                                 Y2rb, Y2sb, Y2ra, Y2sa);
    agg_pool<<<dim3(2500, 2), 256, 0, stream>>>(Y2sb, Y2rb, Y2sa, Y2ra, species,
                                                adj, deg, b2b, b2a, crys, pooled);
    final2<<<NCRYS * 2, 64, 0, stream>>>(pooled, crys, fcW, fcb, out);
}